// Round 6
// baseline (4096.141 us; speedup 1.0000x reference)
//
#include <hip/hip_runtime.h>
#include <math.h>

// FermiNet Ansatz_fb forward: 1 block (256 thr) per walker.
// R6: LDS-pipe de-bottleneck. sv state in REGISTERS (thread j = column j);
// broadcast operands (sv rows, pair-mean rows, mu/md) in a global rows[]
// mirror read via VMEM same-address float4 loads (vL1 broadcast), NOT LDS.
// LDS holds only pv (f32) + small geometry -> ~52.7KB -> 3 blocks/CU.
// asm("+v") blocks uniform->SMEM promotion (scalar L1 incoherent with our
// in-kernel vector stores). f32 numerics everywhere (absmax must stay 0.5).

namespace {

constexpr float SQRT3 = 1.7320508075688772f;

__device__ __forceinline__ float tanh_fast(float x) {
  float e = __expf(2.f * x);
  return 1.f - 2.f * __builtin_amdgcn_rcpf(e + 1.f);
}

__device__ __forceinline__ void fma20(float* a, const float4 r0, const float4 r1,
                                      const float4 r2, const float4 r3, const float4 r4,
                                      const float w) {
  a[0] = fmaf(r0.x, w, a[0]);   a[1] = fmaf(r0.y, w, a[1]);
  a[2] = fmaf(r0.z, w, a[2]);   a[3] = fmaf(r0.w, w, a[3]);
  a[4] = fmaf(r1.x, w, a[4]);   a[5] = fmaf(r1.y, w, a[5]);
  a[6] = fmaf(r1.z, w, a[6]);   a[7] = fmaf(r1.w, w, a[7]);
  a[8] = fmaf(r2.x, w, a[8]);   a[9] = fmaf(r2.y, w, a[9]);
  a[10] = fmaf(r2.z, w, a[10]); a[11] = fmaf(r2.w, w, a[11]);
  a[12] = fmaf(r3.x, w, a[12]); a[13] = fmaf(r3.y, w, a[13]);
  a[14] = fmaf(r3.z, w, a[14]); a[15] = fmaf(r3.w, w, a[15]);
  a[16] = fmaf(r4.x, w, a[16]); a[17] = fmaf(r4.y, w, a[17]);
  a[18] = fmaf(r4.z, w, a[18]); a[19] = fmaf(r4.w, w, a[19]);
}

__global__ __launch_bounds__(256, 3) void ansatz_fused(
    const float* __restrict__ r,     // [B,20,3]
    const float* __restrict__ a_g,   // [4,3]
    const float* __restrict__ s_w0,  // [56,256]
    const float* __restrict__ s_b0,  // [256]
    const float* __restrict__ s_w,   // [3,832,256]
    const float* __restrict__ s_b,   // [3,256]
    const float* __restrict__ p_w0,  // [4,32]
    const float* __restrict__ p_b0,  // [32]
    const float* __restrict__ p_w,   // [3,32,32]
    const float* __restrict__ p_b,   // [3,32]
    const float* __restrict__ vu_w, const float* __restrict__ vu_b,
    const float* __restrict__ vd_w, const float* __restrict__ vd_b,
    const float* __restrict__ wu_w, const float* __restrict__ wu_b,
    const float* __restrict__ wd_w, const float* __restrict__ wd_b,
    const float* __restrict__ wf_w,  // [16]
    float* __restrict__ ws,          // [B][12032] scratch
    float* __restrict__ out)         // [B]
{
  const int b = blockIdx.x;
  const int tid = threadIdx.x;

  float* gw = ws + (size_t)b * 12032;
  float* rows  = gw;          // [320][20]: k<256 sv cols, 256..287 pu, 288..319 pd
  float* gmu   = gw + 6400;   // [256]
  float* gmd   = gw + 6656;   // [256]
  float* rows2 = gw + 6912;   // [256][20]: su at [0..9], sd at [10..19]

  __shared__ __align__(16) float pv[12800];  // later: orb [32][100] + lu/sg
  __shared__ float rl[20][3];
  __shared__ float apos[4][3];
  __shared__ float lenT[80];
  __shared__ float expv[20];
  __shared__ float l0mu[16], l0md[16];
  __shared__ float l0pu[80], l0pd[80];

  // ---- geometry ----
  if (tid < 60) (&rl[0][0])[tid] = r[b * 60 + tid];
  if (tid >= 64 && tid < 76) (&apos[0][0])[tid - 64] = a_g[tid - 64];
  __syncthreads();

  if (tid < 80) {
    int at = tid / 20, e = tid % 20;
    float dx = rl[e][0] - apos[at][0];
    float dy = rl[e][1] - apos[at][1];
    float dz = rl[e][2] - apos[at][2];
    lenT[tid] = sqrtf(dx * dx + dy * dy + dz * dz);
  }
  if (tid < 160) {
    int half = tid / 80, rem = tid % 80, c = rem / 20, j2 = rem % 20;
    float s = 0.f;
    for (int i = half * 10; i < half * 10 + 10; ++i) {
      if (c < 3) {
        s += rl[j2][c] - rl[i][c];
      } else if (i == j2) {
        s += SQRT3;
      } else {
        float dx = rl[j2][0] - rl[i][0], dy = rl[j2][1] - rl[i][1], dz = rl[j2][2] - rl[i][2];
        s += sqrtf(dx * dx + dy * dy + dz * dz);
      }
    }
    (half ? l0pd : l0pu)[c * 20 + j2] = s * 0.1f;
  }
  __syncthreads();

  if (tid < 20) {
    float s = 0.f;
#pragma unroll
    for (int at = 0; at < 4; ++at) s += __expf(-lenT[at * 20 + tid]);
    expv[tid] = s;
  }
  if (tid < 32) {
    int k = tid & 15, half = tid >> 4;
    int at = k >> 2, comp = k & 3;
    float s = 0.f;
    for (int e = half * 10; e < half * 10 + 10; ++e)
      s += (comp < 3) ? (rl[e][comp] - apos[at][comp]) : lenT[at * 20 + e];
    (half ? l0md : l0mu)[k] = s * 0.1f;
  }
  __syncthreads();

  float sv_reg[20];

  // ---- layer 0, single stream -> sv_reg + global stores ----
  {
    const int j = tid;
    float w0s[16], wpp[8];
#pragma unroll
    for (int k = 0; k < 16; ++k) w0s[k] = s_w0[k * 256 + j];
#pragma unroll
    for (int c = 0; c < 8; ++c) wpp[c] = s_w0[(48 + c) * 256 + j];
    float accm = s_b0[j];
#pragma unroll
    for (int k = 0; k < 16; ++k)
      accm += l0mu[k] * s_w0[(16 + k) * 256 + j] + l0md[k] * s_w0[(32 + k) * 256 + j];
#pragma unroll
    for (int e = 0; e < 20; ++e) {
      float acc = accm;
#pragma unroll
      for (int at = 0; at < 4; ++at) {
        acc += (rl[e][0] - apos[at][0]) * w0s[at * 4 + 0];
        acc += (rl[e][1] - apos[at][1]) * w0s[at * 4 + 1];
        acc += (rl[e][2] - apos[at][2]) * w0s[at * 4 + 2];
        acc += lenT[at * 20 + e] * w0s[at * 4 + 3];
      }
#pragma unroll
      for (int c = 0; c < 4; ++c)
        acc += l0pu[c * 20 + e] * wpp[c] + l0pd[c * 20 + e] * wpp[4 + c];
      sv_reg[e] = tanh_fast(acc);
    }
    float su_ = 0.f, sd_ = 0.f;
#pragma unroll
    for (int e = 0; e < 10; ++e) su_ += sv_reg[e];
#pragma unroll
    for (int e = 10; e < 20; ++e) sd_ += sv_reg[e];
    gmu[tid] = su_ * 0.1f;
    gmd[tid] = sd_ * 0.1f;
    float4* rw = (float4*)&rows[tid * 20];
    rw[0] = make_float4(sv_reg[0], sv_reg[1], sv_reg[2], sv_reg[3]);
    rw[1] = make_float4(sv_reg[4], sv_reg[5], sv_reg[6], sv_reg[7]);
    rw[2] = make_float4(sv_reg[8], sv_reg[9], sv_reg[10], sv_reg[11]);
    rw[3] = make_float4(sv_reg[12], sv_reg[13], sv_reg[14], sv_reg[15]);
    rw[4] = make_float4(sv_reg[16], sv_reg[17], sv_reg[18], sv_reg[19]);
  }
  // ---- layer 0, pair stream -> pv (LDS) ----
  {
    const int c = tid & 31;
    float pw0c[4];
#pragma unroll
    for (int k = 0; k < 4; ++k) pw0c[k] = p_w0[k * 32 + c];
    const float pb0c = p_b0[c];
    for (int s = 0; s < 50; ++s) {
      int o = tid + 256 * s;
      int ij = o >> 5, i = ij / 20, j2 = ij % 20;
      float dx = rl[j2][0] - rl[i][0], dy = rl[j2][1] - rl[i][1], dz = rl[j2][2] - rl[i][2];
      float len = (i == j2) ? SQRT3 : sqrtf(dx * dx + dy * dy + dz * dz);
      pv[o] = tanh_fast(pb0c + dx * pw0c[0] + dy * pw0c[1] + dz * pw0c[2] + len * pw0c[3]);
    }
  }
  __threadfence_block();
  __syncthreads();

  // ---- residual layers + final means pass ----
  for (int l = 0; l < 4; ++l) {
    // pair means from pv -> global rows[256..319]
#pragma unroll
    for (int t5 = 0; t5 < 5; ++t5) {
      int t = tid + 256 * t5;
      int half = t / 640, rem = t % 640, j2 = rem >> 5, c = rem & 31;
      int base = half * 6400 + j2 * 32 + c;
      float s = 0.f;
#pragma unroll
      for (int i = 0; i < 10; ++i) s += pv[base + i * 640];
      rows[(256 + half * 32 + c) * 20 + j2] = s * 0.1f;
    }
    __threadfence_block();
    __syncthreads();
    if (l == 3) break;

    const float* Wj = s_w + l * 832 * 256 + tid;

    // phase 1: means (rank-1) contribution
    float m0 = 0.f, m1 = 0.f, m2 = 0.f, m3 = 0.f;
    for (int k = 0; k < 256; k += 4) {
      int mo = k;
      asm volatile("" : "+v"(mo));
      float4 u = *(const float4*)&gmu[mo];
      float4 d = *(const float4*)&gmd[mo];
      m0 = fmaf(u.x, Wj[(256 + k) * 256], m0);
      m1 = fmaf(u.y, Wj[(257 + k) * 256], m1);
      m2 = fmaf(u.z, Wj[(258 + k) * 256], m2);
      m3 = fmaf(u.w, Wj[(259 + k) * 256], m3);
      m0 = fmaf(d.x, Wj[(512 + k) * 256], m0);
      m1 = fmaf(d.y, Wj[(513 + k) * 256], m1);
      m2 = fmaf(d.z, Wj[(514 + k) * 256], m2);
      m3 = fmaf(d.w, Wj[(515 + k) * 256], m3);
    }

    // phase 2+3 unified: 320 broadcast rows (sv, pu, pd)
    float sacc[20];
#pragma unroll
    for (int e = 0; e < 20; ++e) sacc[e] = 0.f;
    for (int k = 0; k < 320; ++k) {
      int ro = k * 20;
      asm volatile("" : "+v"(ro));
      const float4* rp = (const float4*)(rows + ro);
      float4 r0 = rp[0], r1 = rp[1], r2 = rp[2], r3 = rp[3], r4 = rp[4];
      int wr = k + ((k >> 8) << 9);  // k<256 -> k ; 256..319 -> k+512
      float w = Wj[wr * 256];
      fma20(sacc, r0, r1, r2, r3, r4, w);
    }
    __syncthreads();  // all reads of rows done before overwrite

    float accm = s_b[l * 256 + tid] + ((m0 + m1) + (m2 + m3));
    float su_ = 0.f, sd_ = 0.f;
#pragma unroll
    for (int e = 0; e < 20; ++e) {
      sv_reg[e] += tanh_fast(sacc[e] + accm);
      if (e < 10) su_ += sv_reg[e]; else sd_ += sv_reg[e];
    }
    gmu[tid] = su_ * 0.1f;
    gmd[tid] = sd_ * 0.1f;
    {
      float4* rw = (float4*)&rows[tid * 20];
      rw[0] = make_float4(sv_reg[0], sv_reg[1], sv_reg[2], sv_reg[3]);
      rw[1] = make_float4(sv_reg[4], sv_reg[5], sv_reg[6], sv_reg[7]);
      rw[2] = make_float4(sv_reg[8], sv_reg[9], sv_reg[10], sv_reg[11]);
      rw[3] = make_float4(sv_reg[12], sv_reg[13], sv_reg[14], sv_reg[15]);
      rw[4] = make_float4(sv_reg[16], sv_reg[17], sv_reg[18], sv_reg[19]);
    }

    // pair stream: single pass; each wave owns its pv rows end-to-end
    {
      const float* PW = p_w + l * 1024;
      const int c = tid & 31;
      float pwc[32];
#pragma unroll
      for (int k = 0; k < 32; ++k) pwc[k] = PW[k * 32 + c];
      const float pbc = p_b[l * 32 + c];
      for (int s = 0; s < 50; ++s) {
        int o = tid + 256 * s;
        const float4* q4 = (const float4*)&pv[(o >> 5) << 5];
        float row[32];
#pragma unroll
        for (int q = 0; q < 8; ++q) *(float4*)&row[4 * q] = q4[q];
        float acc = pbc;
#pragma unroll
        for (int k = 0; k < 32; ++k) acc = fmaf(row[k], pwc[k], acc);
        pv[o] = row[c] + tanh_fast(acc);
      }
    }
    __threadfence_block();
    __syncthreads();
  }

  // ---- vu/vd heads (fused: one pass over rows serves both) ----
  {
    const float* Wu = vu_w + tid;
    const float* Wd = vd_w + tid;
    float au[10], ad[10];
#pragma unroll
    for (int e = 0; e < 10; ++e) { au[e] = 0.f; ad[e] = 0.f; }
    for (int k = 0; k < 320; ++k) {
      int ro = k * 20;
      asm volatile("" : "+v"(ro));
      const float4* rp = (const float4*)(rows + ro);
      float4 r0 = rp[0], r1 = rp[1], r2 = rp[2], r3 = rp[3], r4 = rp[4];
      int wr = k + ((k >> 8) << 9);
      float wu = Wu[wr * 256], wd = Wd[wr * 256];
      au[0] = fmaf(r0.x, wu, au[0]); au[1] = fmaf(r0.y, wu, au[1]);
      au[2] = fmaf(r0.z, wu, au[2]); au[3] = fmaf(r0.w, wu, au[3]);
      au[4] = fmaf(r1.x, wu, au[4]); au[5] = fmaf(r1.y, wu, au[5]);
      au[6] = fmaf(r1.z, wu, au[6]); au[7] = fmaf(r1.w, wu, au[7]);
      au[8] = fmaf(r2.x, wu, au[8]); au[9] = fmaf(r2.y, wu, au[9]);
      ad[0] = fmaf(r2.z, wd, ad[0]); ad[1] = fmaf(r2.w, wd, ad[1]);
      ad[2] = fmaf(r3.x, wd, ad[2]); ad[3] = fmaf(r3.y, wd, ad[3]);
      ad[4] = fmaf(r3.z, wd, ad[4]); ad[5] = fmaf(r3.w, wd, ad[5]);
      ad[6] = fmaf(r4.x, wd, ad[6]); ad[7] = fmaf(r4.y, wd, ad[7]);
      ad[8] = fmaf(r4.z, wd, ad[8]); ad[9] = fmaf(r4.w, wd, ad[9]);
    }
    float a0 = 0.f, a1 = 0.f, b0 = 0.f, b1 = 0.f;
    for (int k = 0; k < 256; k += 2) {
      int mo = k;
      asm volatile("" : "+v"(mo));
      float2 u = *(const float2*)&gmu[mo];
      float2 d = *(const float2*)&gmd[mo];
      a0 = fmaf(u.x, Wu[(256 + k) * 256], a0);
      a1 = fmaf(u.y, Wu[(257 + k) * 256], a1);
      a0 = fmaf(d.x, Wu[(512 + k) * 256], a0);
      a1 = fmaf(d.y, Wu[(513 + k) * 256], a1);
      b0 = fmaf(u.x, Wd[(256 + k) * 256], b0);
      b1 = fmaf(u.y, Wd[(257 + k) * 256], b1);
      b0 = fmaf(d.x, Wd[(512 + k) * 256], b0);
      b1 = fmaf(d.y, Wd[(513 + k) * 256], b1);
    }
    const float accu = vu_b[tid] + a0 + a1;
    const float accd = vd_b[tid] + b0 + b1;
    float* dst = &rows2[tid * 20];
#pragma unroll
    for (int e = 0; e < 10; ++e) dst[e] = tanh_fast(au[e] + accu);
#pragma unroll
    for (int e = 0; e < 10; ++e) dst[10 + e] = tanh_fast(ad[e] + accd);
  }
  __threadfence_block();
  __syncthreads();

  // ---- orbital matrices -> orb (overlays pv) ----
  float* orb = pv;          // [32][100]
  float* lu_s = pv + 3200;  // [32]
  float* sg_s = pv + 3232;  // [32]
  for (int t = tid; t < 320; t += 256) {
    const int mat = t / 160, col = t % 160;
    const float* Wc = (mat ? wd_w : wu_w) + col;
    const float bb = (mat ? wd_b : wu_b)[col];
    float acc[10];
#pragma unroll
    for (int e = 0; e < 10; ++e) acc[e] = 0.f;
    for (int k = 0; k < 256; ++k) {
      int ro = k * 20 + mat * 10;
      asm volatile("" : "+v"(ro));
      const float* rp = rows2 + ro;
      float2 q0 = *(const float2*)rp;
      float2 q1 = *(const float2*)(rp + 2);
      float2 q2 = *(const float2*)(rp + 4);
      float2 q3 = *(const float2*)(rp + 6);
      float2 q4 = *(const float2*)(rp + 8);
      float w = Wc[k * 160];
      acc[0] = fmaf(q0.x, w, acc[0]); acc[1] = fmaf(q0.y, w, acc[1]);
      acc[2] = fmaf(q1.x, w, acc[2]); acc[3] = fmaf(q1.y, w, acc[3]);
      acc[4] = fmaf(q2.x, w, acc[4]); acc[5] = fmaf(q2.y, w, acc[5]);
      acc[6] = fmaf(q3.x, w, acc[6]); acc[7] = fmaf(q3.y, w, acc[7]);
      acc[8] = fmaf(q4.x, w, acc[8]); acc[9] = fmaf(q4.y, w, acc[9]);
    }
    const int d = col / 10, jo = col % 10;
#pragma unroll
    for (int e = 0; e < 10; ++e)
      orb[(mat * 16 + d) * 100 + e * 10 + jo] = (acc[e] + bb) * expv[mat * 10 + e];
  }
  __syncthreads();

  // ---- slogdet: one 10x10 partial-pivot LU per thread ----
  if (tid < 32) {
    float* M = orb + tid * 100;
    float ldet = 0.f, sg = 1.f;
    for (int c = 0; c < 10; ++c) {
      int p = c;
      float mx = fabsf(M[c * 10 + c]);
      for (int rr = c + 1; rr < 10; ++rr) {
        float v = fabsf(M[rr * 10 + c]);
        if (v > mx) { mx = v; p = rr; }
      }
      if (p != c) {
        sg = -sg;
        for (int cc = c; cc < 10; ++cc) {
          float tmp = M[c * 10 + cc];
          M[c * 10 + cc] = M[p * 10 + cc];
          M[p * 10 + cc] = tmp;
        }
      }
      float piv = M[c * 10 + c];
      if (piv < 0.f) sg = -sg;
      ldet += logf(fabsf(piv));
      float inv = 1.f / piv;
      for (int rr = c + 1; rr < 10; ++rr) {
        float f = M[rr * 10 + c] * inv;
        for (int cc = c + 1; cc < 10; ++cc) M[rr * 10 + cc] -= f * M[c * 10 + cc];
      }
    }
    lu_s[tid] = ldet;
    sg_s[tid] = sg;
  }
  __syncthreads();

  if (tid == 0) {
    float mx = -1e30f;
    float l[16], sgn[16];
#pragma unroll
    for (int d = 0; d < 16; ++d) {
      l[d] = lu_s[d] + lu_s[16 + d];
      sgn[d] = sg_s[d] * sg_s[16 + d];
      mx = fmaxf(mx, l[d]);
    }
    float psi = 0.f;
#pragma unroll
    for (int d = 0; d < 16; ++d) psi += sgn[d] * __expf(l[d] - mx) * wf_w[d];
    out[b] = logf(fabsf(psi)) + mx;
  }
}

}  // namespace

extern "C" void kernel_launch(void* const* d_in, const int* in_sizes, int n_in,
                              void* d_out, int out_size, void* d_ws, size_t ws_size,
                              hipStream_t stream) {
  const float* r = (const float*)d_in[0];
  const float* a = (const float*)d_in[1];
  const float* s_w0 = (const float*)d_in[2];
  const float* s_b0 = (const float*)d_in[3];
  const float* s_w = (const float*)d_in[4];
  const float* s_b = (const float*)d_in[5];
  const float* p_w0 = (const float*)d_in[6];
  const float* p_b0 = (const float*)d_in[7];
  const float* p_w = (const float*)d_in[8];
  const float* p_b = (const float*)d_in[9];
  const float* vu_w = (const float*)d_in[10];
  const float* vu_b = (const float*)d_in[11];
  const float* vd_w = (const float*)d_in[12];
  const float* vd_b = (const float*)d_in[13];
  const float* wu_w = (const float*)d_in[14];
  const float* wu_b = (const float*)d_in[15];
  const float* wd_w = (const float*)d_in[16];
  const float* wd_b = (const float*)d_in[17];
  const float* wf_w = (const float*)d_in[18];

  const int nb = in_sizes[0] / 60;  // [B,20,3]
  // scratch: 12032 floats/walker (48.1KB). R5 evidence: ws_size >= 105MB.
  ansatz_fused<<<dim3(nb), dim3(256), 0, stream>>>(
      r, a, s_w0, s_b0, s_w, s_b, p_w0, p_b0, p_w, p_b,
      vu_w, vu_b, vd_w, vd_b, wu_w, wu_b, wd_w, wd_b, wf_w,
      (float*)d_ws, (float*)d_out);
}

// Round 9
// 3577.461 us; speedup vs baseline: 1.1450x; 1.1450x over previous
//
#include <hip/hip_runtime.h>
#include <math.h>

// FermiNet Ansatz_fb forward, R9: MFMA with 3-WAY BF16 SPLIT (6 products).
// x = h+m+l (three bf16, repr err ~2^-27); products {hH,mH,hM,lH,mM,hL} leave
// error below f32 eps. R8's split-2 (2^-18) gave absmax 3.0; this targets 0.5.
// Layer 0 also on MFMA (A0 tile, no state readback quantization).
// kt-outer loops: A-frags loaded once per kt, reused across 4 nt tiles.
// pv stream f32 VALU in global scratch (R5-proven). 2 blocks/CU (LDS ~70KB).

namespace {

typedef __attribute__((ext_vector_type(8))) short short8v;
typedef __attribute__((ext_vector_type(4))) float f32x4;

constexpr float SQRT3 = 1.7320508075688772f;
constexpr int AST = 264;
constexpr int A2ST = 72;

constexpr size_t MSZ = 212992;   // 832*256
constexpr size_t WSZ = 40960;    // 256*160
constexpr size_t SW0SZ = 16384;  // 64*256
constexpr size_t OFF_VU = 3 * MSZ;
constexpr size_t OFF_VD = 4 * MSZ;
constexpr size_t OFF_WU = 5 * MSZ;
constexpr size_t OFF_WD = 5 * MSZ + WSZ;
constexpr size_t OFF_SW0 = 5 * MSZ + 2 * WSZ;
constexpr size_t PLANE = 5 * MSZ + 2 * WSZ + SW0SZ;  // 1,163,264 shorts
constexpr size_t PV_OFF_FLOATS = 3 * PLANE / 2;

__device__ __forceinline__ float bfh2f(unsigned short h) {
  union { unsigned u; float f; } x; x.u = ((unsigned)h) << 16; return x.f;
}
__device__ __forceinline__ unsigned short f2bf(float f) {
  union { float f; unsigned u; } x; x.f = f;
  unsigned r = x.u + 0x7fffu + ((x.u >> 16) & 1u);
  return (unsigned short)(r >> 16);
}
__device__ __forceinline__ void split3(float x, unsigned short& h, unsigned short& m,
                                       unsigned short& l) {
  h = f2bf(x);
  float r1 = x - bfh2f(h);
  m = f2bf(r1);
  l = f2bf(r1 - bfh2f(m));
}
__device__ __forceinline__ float tanh_fast(float x) {
  float e = __expf(2.f * x);
  return 1.f - 2.f * __builtin_amdgcn_rcpf(e + 1.f);
}
__device__ __forceinline__ f32x4 mfma16(short8v a, short8v b, f32x4 c) {
  return __builtin_amdgcn_mfma_f32_16x16x32_bf16(a, b, c, 0, 0, 0);
}
__device__ __forceinline__ void mfma6(f32x4& acc, short8v ah, short8v am, short8v al,
                                      short8v bh, short8v bm, short8v bl) {
  acc = mfma16(ah, bh, acc);
  acc = mfma16(am, bh, acc);
  acc = mfma16(ah, bm, acc);
  acc = mfma16(al, bh, acc);
  acc = mfma16(am, bm, acc);
  acc = mfma16(ah, bl, acc);
}
__device__ __forceinline__ short8v ldfragA(const unsigned short* Ab, int row, int k0) {
  return *(const short8v*)&Ab[row * AST + k0];
}
__device__ __forceinline__ short8v ldfragA2(const unsigned short* Ab, int row, int k0) {
  return *(const short8v*)&Ab[row * A2ST + k0];
}
__device__ __forceinline__ short8v ldfragB(const unsigned short* __restrict__ plane,
                                           size_t off, int KT, int nt, int kt, int ln) {
  return *(const short8v*)(plane + off + (size_t)(((nt * KT + kt) * 64 + ln) * 8));
}

// ---------------- prep: f32 weights -> 3-plane split-bf16 fragments ----------------
__global__ void prep_weights(const float* __restrict__ s_w,
                             const float* __restrict__ vu_w,
                             const float* __restrict__ vd_w,
                             const float* __restrict__ wu_w,
                             const float* __restrict__ wd_w,
                             const float* __restrict__ s_w0,
                             unsigned short* __restrict__ wsb) {
  int idx = blockIdx.x * 256 + threadIdx.x;
  const float* src; int N, KT, kmax; size_t dstoff; int local;
  if (idx < 133120) {               // 5 big matrices (832x256)
    int mi = idx / 26624; local = idx % 26624;
    N = 256; KT = 26; kmax = 832;
    src = (mi < 3) ? (s_w + (size_t)mi * MSZ) : (mi == 3 ? vu_w : vd_w);
    dstoff = (size_t)mi * MSZ;
  } else if (idx < 143360) {        // wu, wd (256x160)
    int j = idx - 133120; int mi = j / 5120; local = j % 5120;
    N = 160; KT = 8; kmax = 256;
    src = mi ? wd_w : wu_w;
    dstoff = OFF_WU + (size_t)mi * WSZ;
  } else if (idx < 145408) {        // s_w0 (56x256, padded to 64)
    local = idx - 143360;
    N = 256; KT = 2; kmax = 56;
    src = s_w0;
    dstoff = OFF_SW0;
  } else return;
  int nt = local / (KT * 64);
  int rem = local % (KT * 64);
  int kt = rem / 64, ln = rem % 64;
  int g = ln >> 4, q = ln & 15;
  short8v vh, vm, vl;
#pragma unroll
  for (int j2 = 0; j2 < 8; ++j2) {
    int k = kt * 32 + g * 8 + j2;
    float x = (k < kmax) ? src[(size_t)k * N + nt * 16 + q] : 0.f;
    unsigned short h, m, l;
    split3(x, h, m, l);
    vh[j2] = (short)h; vm[j2] = (short)m; vl[j2] = (short)l;
  }
  *(short8v*)(wsb + dstoff + (size_t)local * 8) = vh;
  *(short8v*)(wsb + PLANE + dstoff + (size_t)local * 8) = vm;
  *(short8v*)(wsb + 2 * PLANE + dstoff + (size_t)local * 8) = vl;
}

// ---------------- main kernel ----------------
template <bool GPV>
__global__ __launch_bounds__(256, GPV ? 2 : 1) void ansatz_fused(
    const float* __restrict__ r, const float* __restrict__ a_g,
    const float* __restrict__ s_b0, const float* __restrict__ s_b,
    const float* __restrict__ p_w0, const float* __restrict__ p_b0,
    const float* __restrict__ p_w, const float* __restrict__ p_b,
    const float* __restrict__ vu_b, const float* __restrict__ vd_b,
    const float* __restrict__ wu_b, const float* __restrict__ wd_b,
    const float* __restrict__ wf_w,
    const unsigned short* __restrict__ wsb,
    float* __restrict__ wspv,
    float* __restrict__ out) {
  const int b = blockIdx.x;
  const int tid = threadIdx.x;
  const int ln = tid & 63, w = tid >> 6;
  const int g = ln >> 4, q = ln & 15;
  const unsigned short* __restrict__ P0 = wsb;
  const unsigned short* __restrict__ P1 = wsb + PLANE;
  const unsigned short* __restrict__ P2 = wsb + 2 * PLANE;

  // LDS: A planes 3x[32][264]=50688B, A2 planes 3x[32][72]=13824B, contrib 4KB
  __shared__ __align__(16) unsigned short abuf_all[32256];
  __shared__ __align__(16) float contrib[1024];
  __shared__ __align__(16) float pvlds[GPV ? 4 : 12800];
  __shared__ float rl[20][3], apos[4][3], lenT[80], expv[20];
  __shared__ float l0mu[16], l0md[16], l0pu[80], l0pd[80];

  unsigned short* Ah = abuf_all;
  unsigned short* Am = abuf_all + 8448;
  unsigned short* Al = abuf_all + 16896;
  unsigned short* A2h = abuf_all + 25344;
  unsigned short* A2m = abuf_all + 27648;
  unsigned short* A2l = abuf_all + 29952;
  float* pvg = GPV ? (wspv + (size_t)b * 12800) : (float*)pvlds;

  float st0[4][4], st1[4][4];

  // ---- phase 0: zero A/A2 planes, load geometry ----
  {
    unsigned int* az = (unsigned int*)abuf_all;
    for (int t = tid; t < 16128; t += 256) az[t] = 0u;
  }
  if (tid < 60) (&rl[0][0])[tid] = r[b * 60 + tid];
  if (tid >= 64 && tid < 76) (&apos[0][0])[tid - 64] = a_g[tid - 64];
  __syncthreads();

  if (tid < 80) {
    int at = tid / 20, e = tid % 20;
    float dx = rl[e][0] - apos[at][0], dy = rl[e][1] - apos[at][1], dz = rl[e][2] - apos[at][2];
    lenT[tid] = sqrtf(dx * dx + dy * dy + dz * dz);
  }
  if (tid < 160) {
    int half = tid / 80, rem = tid % 80, c = rem / 20, j2 = rem % 20;
    float s = 0.f;
    for (int i = half * 10; i < half * 10 + 10; ++i) {
      if (c < 3) s += rl[j2][c] - rl[i][c];
      else if (i == j2) s += SQRT3;
      else {
        float dx = rl[j2][0] - rl[i][0], dy = rl[j2][1] - rl[i][1], dz = rl[j2][2] - rl[i][2];
        s += sqrtf(dx * dx + dy * dy + dz * dz);
      }
    }
    (half ? l0pd : l0pu)[c * 20 + j2] = s * 0.1f;
  }
  __syncthreads();
  if (tid < 20) {
    float s = 0.f;
#pragma unroll
    for (int at = 0; at < 4; ++at) s += __expf(-lenT[at * 20 + tid]);
    expv[tid] = s;
  }
  if (tid < 32) {
    int k = tid & 15, half = tid >> 4, at = k >> 2, comp = k & 3;
    float s = 0.f;
    for (int e = half * 10; e < half * 10 + 10; ++e)
      s += (comp < 3) ? (rl[e][comp] - apos[at][comp]) : lenT[at * 20 + e];
    (half ? l0md : l0mu)[k] = s * 0.1f;
  }
  __syncthreads();

  // ---- A0 tile build ([20 rows][56 cols], split3) + layer-0 pair stream ----
  for (int t = tid; t < 1120; t += 256) {
    int row = t / 56, col = t % 56;
    float v;
    if (col < 16) {
      int at = col >> 2, comp = col & 3;
      v = (comp < 3) ? (rl[row][comp] - apos[at][comp]) : lenT[at * 20 + row];
    } else if (col < 32) v = l0mu[col - 16];
    else if (col < 48) v = l0md[col - 32];
    else if (col < 52) v = l0pu[(col - 48) * 20 + row];
    else v = l0pd[(col - 52) * 20 + row];
    unsigned short h, m, l;
    split3(v, h, m, l);
    Ah[row * AST + col] = h; Am[row * AST + col] = m; Al[row * AST + col] = l;
  }
  {
    const int c = tid & 31;
    float pw0c[4];
#pragma unroll
    for (int k = 0; k < 4; ++k) pw0c[k] = p_w0[k * 32 + c];
    const float pb0c = p_b0[c];
    for (int s = 0; s < 50; ++s) {
      int o = tid + 256 * s;
      int ij = o >> 5, i = ij / 20, j2 = ij % 20;
      float dx = rl[j2][0] - rl[i][0], dy = rl[j2][1] - rl[i][1], dz = rl[j2][2] - rl[i][2];
      float len = (i == j2) ? SQRT3 : sqrtf(dx * dx + dy * dy + dz * dz);
      pvg[o] = tanh_fast(pb0c + dx * pw0c[0] + dy * pw0c[1] + dz * pw0c[2] + len * pw0c[3]);
    }
  }
  __threadfence_block();
  __syncthreads();

  // ---- layer 0 GEMM (K=64): st = tanh(A0 @ s_w0 + s_b0), no residual ----
  {
    f32x4 a0acc[4], a1acc[4];
#pragma unroll
    for (int t = 0; t < 4; ++t) {
      a0acc[t] = (f32x4){0.f, 0.f, 0.f, 0.f};
      a1acc[t] = (f32x4){0.f, 0.f, 0.f, 0.f};
    }
#pragma unroll
    for (int kt = 0; kt < 2; ++kt) {
      const int k0 = kt * 32 + g * 8;
      short8v a0h = ldfragA(Ah, q, k0), a0m = ldfragA(Am, q, k0), a0l = ldfragA(Al, q, k0);
      short8v a1h = ldfragA(Ah, 16 + q, k0), a1m = ldfragA(Am, 16 + q, k0),
              a1l = ldfragA(Al, 16 + q, k0);
#pragma unroll
      for (int t = 0; t < 4; ++t) {
        const int nt = 4 * w + t;
        short8v bh = ldfragB(P0, OFF_SW0, 2, nt, kt, ln);
        short8v bm = ldfragB(P1, OFF_SW0, 2, nt, kt, ln);
        short8v bl = ldfragB(P2, OFF_SW0, 2, nt, kt, ln);
        mfma6(a0acc[t], a0h, a0m, a0l, bh, bm, bl);
        mfma6(a1acc[t], a1h, a1m, a1l, bh, bm, bl);
      }
    }
#pragma unroll
    for (int t = 0; t < 4; ++t) {
      const int col = q + 16 * (4 * w + t);
      const float bb = s_b0[col];
#pragma unroll
      for (int i = 0; i < 4; ++i) st0[t][i] = tanh_fast(a0acc[t][i] + bb);
#pragma unroll
      for (int i = 0; i < 4; ++i)
        st1[t][i] = (g == 0) ? tanh_fast(a1acc[t][i] + bb) : 0.f;
    }
  }
  __syncthreads();
  // write state -> A planes (split3), rows 0..31 all cols
#pragma unroll
  for (int t = 0; t < 4; ++t) {
    const int col = q + 16 * (4 * w + t);
#pragma unroll
    for (int i = 0; i < 4; ++i) {
      unsigned short h, m, l;
      split3(st0[t][i], h, m, l);
      Ah[(4 * g + i) * AST + col] = h; Am[(4 * g + i) * AST + col] = m;
      Al[(4 * g + i) * AST + col] = l;
      split3(st1[t][i], h, m, l);
      Ah[(16 + 4 * g + i) * AST + col] = h; Am[(16 + 4 * g + i) * AST + col] = m;
      Al[(16 + 4 * g + i) * AST + col] = l;
    }
  }
  __syncthreads();

  // ---- residual layers (l=0..2) + final means pass (l=3) ----
  for (int l = 0; l < 4; ++l) {
    // pair means from pvg -> A2 planes (split3)
#pragma unroll
    for (int t5 = 0; t5 < 5; ++t5) {
      int t = tid + 256 * t5;
      int half = t / 640, rem = t % 640, j2 = rem >> 5, c = rem & 31;
      int base = half * 6400 + j2 * 32 + c;
      float s = 0.f;
#pragma unroll
      for (int i = 0; i < 10; ++i) s += pvg[base + i * 640];
      unsigned short h, m, lo;
      split3(s * 0.1f, h, m, lo);
      A2h[j2 * A2ST + half * 32 + c] = h;
      A2m[j2 * A2ST + half * 32 + c] = m;
      A2l[j2 * A2ST + half * 32 + c] = lo;
    }
    // mu/md from state -> A rows 20/21 (split3, shfl-reduced)
#pragma unroll
    for (int t = 0; t < 4; ++t) {
      const int col = q + 16 * (4 * w + t);
      float s0 = st0[t][0] + st0[t][1], s01 = s0 + st0[t][2] + st0[t][3];
      float pu = (g <= 1) ? s01 : (g == 2 ? s0 : 0.f);
      float pd;
      if (g == 2) pd = st0[t][2] + st0[t][3];
      else if (g == 3) pd = s01;
      else if (g == 0) pd = st1[t][0] + st1[t][1] + st1[t][2] + st1[t][3];
      else pd = 0.f;
      float ru = pu; ru += __shfl_xor(ru, 16); ru += __shfl_xor(ru, 32);
      float rd = pd; rd += __shfl_xor(rd, 16); rd += __shfl_xor(rd, 32);
      if (ln < 16) {
        unsigned short h, m, lo;
        split3(0.1f * ru, h, m, lo);
        Ah[20 * AST + col] = h; Am[20 * AST + col] = m; Al[20 * AST + col] = lo;
        split3(0.1f * rd, h, m, lo);
        Ah[21 * AST + col] = h; Am[21 * AST + col] = m; Al[21 * AST + col] = lo;
      }
    }
    __syncthreads();
    if (l == 3) break;

    const size_t swoff = (size_t)l * MSZ;

    // mini-GEMMs: mu @ W_mu (B kt 8..15, D row 4) ; md @ W_md (16..23, D row 5)
    {
      f32x4 accU[4], accD[4];
#pragma unroll
      for (int t = 0; t < 4; ++t) {
        accU[t] = (f32x4){0.f, 0.f, 0.f, 0.f};
        accD[t] = (f32x4){0.f, 0.f, 0.f, 0.f};
      }
      for (int kt = 0; kt < 8; ++kt) {
        const int k0 = kt * 32 + g * 8;
        short8v ah = ldfragA(Ah, 16 + q, k0), am = ldfragA(Am, 16 + q, k0),
                al = ldfragA(Al, 16 + q, k0);
#pragma unroll
        for (int t = 0; t < 4; ++t) {
          const int nt = 4 * w + t;
          short8v bh = ldfragB(P0, swoff, 26, nt, 8 + kt, ln);
          short8v bm = ldfragB(P1, swoff, 26, nt, 8 + kt, ln);
          short8v bl = ldfragB(P2, swoff, 26, nt, 8 + kt, ln);
          mfma6(accU[t], ah, am, al, bh, bm, bl);
          bh = ldfragB(P0, swoff, 26, nt, 16 + kt, ln);
          bm = ldfragB(P1, swoff, 26, nt, 16 + kt, ln);
          bl = ldfragB(P2, swoff, 26, nt, 16 + kt, ln);
          mfma6(accD[t], ah, am, al, bh, bm, bl);
        }
      }
#pragma unroll
      for (int t = 0; t < 4; ++t) {
        const int col = q + 16 * (4 * w + t);
        if (g == 1) { contrib[col] = accU[t][0]; contrib[256 + col] = accD[t][1]; }
      }
    }
    __syncthreads();

    // GEMM1: sv (B kt 0..7) + pair A2 (B kt 24/25)
    {
      f32x4 a0acc[4], a1acc[4];
#pragma unroll
      for (int t = 0; t < 4; ++t) {
        a0acc[t] = (f32x4){0.f, 0.f, 0.f, 0.f};
        a1acc[t] = (f32x4){0.f, 0.f, 0.f, 0.f};
      }
      for (int kt = 0; kt < 8; ++kt) {
        const int k0 = kt * 32 + g * 8;
        short8v a0h = ldfragA(Ah, q, k0), a0m = ldfragA(Am, q, k0), a0l = ldfragA(Al, q, k0);
        short8v a1h = ldfragA(Ah, 16 + q, k0), a1m = ldfragA(Am, 16 + q, k0),
                a1l = ldfragA(Al, 16 + q, k0);
#pragma unroll
        for (int t = 0; t < 4; ++t) {
          const int nt = 4 * w + t;
          short8v bh = ldfragB(P0, swoff, 26, nt, kt, ln);
          short8v bm = ldfragB(P1, swoff, 26, nt, kt, ln);
          short8v bl = ldfragB(P2, swoff, 26, nt, kt, ln);
          mfma6(a0acc[t], a0h, a0m, a0l, bh, bm, bl);
          mfma6(a1acc[t], a1h, a1m, a1l, bh, bm, bl);
        }
      }
#pragma unroll
      for (int kt = 0; kt < 2; ++kt) {
        const int k0 = kt * 32 + g * 8;
        short8v a0h = ldfragA2(A2h, q, k0), a0m = ldfragA2(A2m, q, k0),
                a0l = ldfragA2(A2l, q, k0);
        short8v a1h = ldfragA2(A2h, 16 + q, k0), a1m = ldfragA2(A2m, 16 + q, k0),
                a1l = ldfragA2(A2l, 16 + q, k0);
#pragma unroll
        for (int t = 0; t < 4; ++t) {
          const int nt = 4 * w + t;
          short8v bh = ldfragB(P0, swoff, 26, nt, 24 + kt, ln);
          short8v bm = ldfragB(P1, swoff, 26, nt, 24 + kt, ln);
          short8v bl = ldfragB(P2, swoff, 26, nt, 24 + kt, ln);
          mfma6(a0acc[t], a0h, a0m, a0l, bh, bm, bl);
          mfma6(a1acc[t], a1h, a1m, a1l, bh, bm, bl);
        }
      }
#pragma unroll
      for (int t = 0; t < 4; ++t) {
        const int col = q + 16 * (4 * w + t);
        const float based = s_b[l * 256 + col] + contrib[col] + contrib[256 + col];
#pragma unroll
        for (int i = 0; i < 4; ++i) st0[t][i] += tanh_fast(a0acc[t][i] + based);
        if (g == 0) {
#pragma unroll
          for (int i = 0; i < 4; ++i) st1[t][i] += tanh_fast(a1acc[t][i] + based);
        }
      }
    }
    __syncthreads();

    // write state -> A planes; pair stream (f32 VALU on pvg)
#pragma unroll
    for (int t = 0; t < 4; ++t) {
      const int col = q + 16 * (4 * w + t);
#pragma unroll
      for (int i = 0; i < 4; ++i) {
        unsigned short h, m, lo;
        split3(st0[t][i], h, m, lo);
        Ah[(4 * g + i) * AST + col] = h; Am[(4 * g + i) * AST + col] = m;
        Al[(4 * g + i) * AST + col] = lo;
        split3(st1[t][i], h, m, lo);
        Ah[(16 + 4 * g + i) * AST + col] = h; Am[(16 + 4 * g + i) * AST + col] = m;
        Al[(16 + 4 * g + i) * AST + col] = lo;
      }
    }
    {
      const float* PW = p_w + l * 1024;
      const int c = tid & 31;
      float pwc[32];
#pragma unroll
      for (int k = 0; k < 32; ++k) pwc[k] = PW[k * 32 + c];
      const float pbc = p_b[l * 32 + c];
      for (int s = 0; s < 50; ++s) {
        int o = tid + 256 * s;
        const float4* q4 = (const float4*)&pvg[(o >> 5) << 5];
        float row[32];
#pragma unroll
        for (int q2 = 0; q2 < 8; ++q2) *(float4*)&row[4 * q2] = q4[q2];
        float acc = pbc;
#pragma unroll
        for (int k = 0; k < 32; ++k) acc = fmaf(row[k], pwc[k], acc);
        pvg[o] = row[c] + tanh_fast(acc);
      }
    }
    __threadfence_block();
    __syncthreads();
  }

  // ---- heads: vu/vd mean mini-GEMMs ----
  for (int hh = 0; hh < 2; ++hh) {
    const size_t hoff = hh ? OFF_VD : OFF_VU;
    f32x4 accU[4], accD[4];
#pragma unroll
    for (int t = 0; t < 4; ++t) {
      accU[t] = (f32x4){0.f, 0.f, 0.f, 0.f};
      accD[t] = (f32x4){0.f, 0.f, 0.f, 0.f};
    }
    for (int kt = 0; kt < 8; ++kt) {
      const int k0 = kt * 32 + g * 8;
      short8v ah = ldfragA(Ah, 16 + q, k0), am = ldfragA(Am, 16 + q, k0),
              al = ldfragA(Al, 16 + q, k0);
#pragma unroll
      for (int t = 0; t < 4; ++t) {
        const int nt = 4 * w + t;
        short8v bh = ldfragB(P0, hoff, 26, nt, 8 + kt, ln);
        short8v bm = ldfragB(P1, hoff, 26, nt, 8 + kt, ln);
        short8v bl = ldfragB(P2, hoff, 26, nt, 8 + kt, ln);
        mfma6(accU[t], ah, am, al, bh, bm, bl);
        bh = ldfragB(P0, hoff, 26, nt, 16 + kt, ln);
        bm = ldfragB(P1, hoff, 26, nt, 16 + kt, ln);
        bl = ldfragB(P2, hoff, 26, nt, 16 + kt, ln);
        mfma6(accD[t], ah, am, al, bh, bm, bl);
      }
    }
#pragma unroll
    for (int t = 0; t < 4; ++t) {
      const int col = q + 16 * (4 * w + t);
      if (g == 1) { contrib[hh * 512 + col] = accU[t][0]; contrib[hh * 512 + 256 + col] = accD[t][1]; }
    }
  }
  __syncthreads();

  // ---- vu GEMM1 (electron rows < 10, tile1 only) ----
  {
    f32x4 acc[4];
#pragma unroll
    for (int t = 0; t < 4; ++t) acc[t] = (f32x4){0.f, 0.f, 0.f, 0.f};
    for (int kt = 0; kt < 8; ++kt) {
      const int k0 = kt * 32 + g * 8;
      short8v a0h = ldfragA(Ah, q, k0), a0m = ldfragA(Am, q, k0), a0l = ldfragA(Al, q, k0);
#pragma unroll
      for (int t = 0; t < 4; ++t) {
        const int nt = 4 * w + t;
        short8v bh = ldfragB(P0, OFF_VU, 26, nt, kt, ln);
        short8v bm = ldfragB(P1, OFF_VU, 26, nt, kt, ln);
        short8v bl = ldfragB(P2, OFF_VU, 26, nt, kt, ln);
        mfma6(acc[t], a0h, a0m, a0l, bh, bm, bl);
      }
    }
#pragma unroll
    for (int kt = 0; kt < 2; ++kt) {
      const int k0 = kt * 32 + g * 8;
      short8v a0h = ldfragA2(A2h, q, k0), a0m = ldfragA2(A2m, q, k0), a0l = ldfragA2(A2l, q, k0);
#pragma unroll
      for (int t = 0; t < 4; ++t) {
        const int nt = 4 * w + t;
        short8v bh = ldfragB(P0, OFF_VU, 26, nt, 24 + kt, ln);
        short8v bm = ldfragB(P1, OFF_VU, 26, nt, 24 + kt, ln);
        short8v bl = ldfragB(P2, OFF_VU, 26, nt, 24 + kt, ln);
        mfma6(acc[t], a0h, a0m, a0l, bh, bm, bl);
      }
    }
#pragma unroll
    for (int t = 0; t < 4; ++t) {
      const int col = q + 16 * (4 * w + t);
      const float based = vu_b[col] + contrib[col] + contrib[256 + col];
#pragma unroll
      for (int i = 0; i < 4; ++i)
        if (4 * g + i < 10) st0[t][i] = tanh_fast(acc[t][i] + based);
    }
  }
  // ---- vd GEMM1 (electron rows 10..19) ----
  {
    f32x4 a0acc[4], a1acc[4];
#pragma unroll
    for (int t = 0; t < 4; ++t) {
      a0acc[t] = (f32x4){0.f, 0.f, 0.f, 0.f};
      a1acc[t] = (f32x4){0.f, 0.f, 0.f, 0.f};
    }
    for (int kt = 0; kt < 8; ++kt) {
      const int k0 = kt * 32 + g * 8;
      short8v a0h = ldfragA(Ah, q, k0), a0m = ldfragA(Am, q, k0), a0l = ldfragA(Al, q, k0);
      short8v a1h = ldfragA(Ah, 16 + q, k0), a1m = ldfragA(Am, 16 + q, k0),
              a1l = ldfragA(Al, 16 + q, k0);
#pragma unroll
      for (int t = 0; t < 4; ++t) {
        const int nt = 4 * w + t;
        short8v bh = ldfragB(P0, OFF_VD, 26, nt, kt, ln);
        short8v bm = ldfragB(P1, OFF_VD, 26, nt, kt, ln);
        short8v bl = ldfragB(P2, OFF_VD, 26, nt, kt, ln);
        mfma6(a0acc[t], a0h, a0m, a0l, bh, bm, bl);
        mfma6(a1acc[t], a1h, a1m, a1l, bh, bm, bl);
      }
    }
#pragma unroll
    for (int kt = 0; kt < 2; ++kt) {
      const int k0 = kt * 32 + g * 8;
      short8v a0h = ldfragA2(A2h, q, k0), a0m = ldfragA2(A2m, q, k0), a0l = ldfragA2(A2l, q, k0);
      short8v a1h = ldfragA2(A2h, 16 + q, k0), a1m = ldfragA2(A2m, 16 + q, k0),
              a1l = ldfragA2(A2l, 16 + q, k0);
#pragma unroll
      for (int t = 0; t < 4; ++t) {
        const int nt = 4 * w + t;
        short8v bh = ldfragB(P0, OFF_VD, 26, nt, 24 + kt, ln);
        short8v bm = ldfragB(P1, OFF_VD, 26, nt, 24 + kt, ln);
        short8v bl = ldfragB(P2, OFF_VD, 26, nt, 24 + kt, ln);
        mfma6(a0acc[t], a0h, a0m, a0l, bh, bm, bl);
        mfma6(a1acc[t], a1h, a1m, a1l, bh, bm, bl);
      }
    }
#pragma unroll
    for (int t = 0; t < 4; ++t) {
      const int col = q + 16 * (4 * w + t);
      const float based = vd_b[col] + contrib[512 + col] + contrib[768 + col];
#pragma unroll
      for (int i = 0; i < 4; ++i)
        if (4 * g + i >= 10) st0[t][i] = tanh_fast(a0acc[t][i] + based);
#pragma unroll
      for (int i = 0; i < 4; ++i)
        st1[t][i] = (g == 0) ? tanh_fast(a1acc[t][i] + based) : 0.f;
    }
  }
  __syncthreads();

  // ---- write head state (s_u rows 0-9, s_d rows 10-19) ----
#pragma unroll
  for (int t = 0; t < 4; ++t) {
    const int col = q + 16 * (4 * w + t);
#pragma unroll
    for (int i = 0; i < 4; ++i) {
      unsigned short h, m, lo;
      split3(st0[t][i], h, m, lo);
      Ah[(4 * g + i) * AST + col] = h; Am[(4 * g + i) * AST + col] = m;
      Al[(4 * g + i) * AST + col] = lo;
      split3(st1[t][i], h, m, lo);
      Ah[(16 + 4 * g + i) * AST + col] = h; Am[(16 + 4 * g + i) * AST + col] = m;
      Al[(16 + 4 * g + i) * AST + col] = lo;
    }
  }
  __syncthreads();

  // ---- w_u / w_d GEMMs -> orb (overlays dead A2/contrib region) ----
  float* orb = (float*)A2h;      // 3264 floats fit in A2's 13824B
  float* lu_s = orb + 3200;
  float* sg_s = orb + 3232;
  for (int nt = w; nt < 10; nt += 4) {
    const int c2 = q + 16 * nt, d = c2 / 10, jo = c2 % 10;
    f32x4 acc = {0.f, 0.f, 0.f, 0.f};
    for (int kt = 0; kt < 8; ++kt) {
      const int k0 = kt * 32 + g * 8;
      short8v a0h = ldfragA(Ah, q, k0), a0m = ldfragA(Am, q, k0), a0l = ldfragA(Al, q, k0);
      short8v bh = ldfragB(P0, OFF_WU, 8, nt, kt, ln);
      short8v bm = ldfragB(P1, OFF_WU, 8, nt, kt, ln);
      short8v bl = ldfragB(P2, OFF_WU, 8, nt, kt, ln);
      mfma6(acc, a0h, a0m, a0l, bh, bm, bl);
    }
    const float bb = wu_b[c2];
#pragma unroll
    for (int i = 0; i < 4; ++i) {
      int row = 4 * g + i;
      if (row < 10) orb[d * 100 + row * 10 + jo] = (acc[i] + bb) * expv[row];
    }
  }
  for (int nt = w; nt < 10; nt += 4) {
    const int c2 = q + 16 * nt, d = c2 / 10, jo = c2 % 10;
    f32x4 a0acc = {0.f, 0.f, 0.f, 0.f}, a1acc = {0.f, 0.f, 0.f, 0.f};
    for (int kt = 0; kt < 8; ++kt) {
      const int k0 = kt * 32 + g * 8;
      short8v a0h = ldfragA(Ah, q, k0), a0m = ldfragA(Am, q, k0), a0l = ldfragA(Al, q, k0);
      short8v a1h = ldfragA(Ah, 16 + q, k0), a1m = ldfragA(Am, 16 + q, k0),
              a1l = ldfragA(Al, 16 + q, k0);
      short8v bh = ldfragB(P0, OFF_WD, 8, nt, kt, ln);
      short8v bm = ldfragB(P1, OFF_WD, 8, nt, kt, ln);
      short8v bl = ldfragB(P2, OFF_WD, 8, nt, kt, ln);
      mfma6(a0acc, a0h, a0m, a0l, bh, bm, bl);
      mfma6(a1acc, a1h, a1m, a1l, bh, bm, bl);
    }
    const float bb = wd_b[c2];
#pragma unroll
    for (int i = 0; i < 4; ++i) {
      int row = 4 * g + i;
      if (row >= 10) orb[(16 + d) * 100 + (row - 10) * 10 + jo] = (a0acc[i] + bb) * expv[row];
    }
    if (g == 0) {
#pragma unroll
      for (int i = 0; i < 4; ++i)
        orb[(16 + d) * 100 + (6 + i) * 10 + jo] = (a1acc[i] + bb) * expv[16 + i];
    }
  }
  __syncthreads();

  // ---- slogdet: one 10x10 partial-pivot LU per thread ----
  if (tid < 32) {
    float* M = orb + tid * 100;
    float ldet = 0.f, sg = 1.f;
    for (int c = 0; c < 10; ++c) {
      int p = c;
      float mx = fabsf(M[c * 10 + c]);
      for (int rr = c + 1; rr < 10; ++rr) {
        float v = fabsf(M[rr * 10 + c]);
        if (v > mx) { mx = v; p = rr; }
      }
      if (p != c) {
        sg = -sg;
        for (int cc = c; cc < 10; ++cc) {
          float tmp = M[c * 10 + cc];
          M[c * 10 + cc] = M[p * 10 + cc];
          M[p * 10 + cc] = tmp;
        }
      }
      float piv = M[c * 10 + c];
      if (piv < 0.f) sg = -sg;
      ldet += logf(fabsf(piv));
      float inv = 1.f / piv;
      for (int rr = c + 1; rr < 10; ++rr) {
        float f = M[rr * 10 + c] * inv;
        for (int cc = c + 1; cc < 10; ++cc) M[rr * 10 + cc] -= f * M[c * 10 + cc];
      }
    }
    lu_s[tid] = ldet;
    sg_s[tid] = sg;
  }
  __syncthreads();

  if (tid == 0) {
    float mx = -1e30f;
    float l2[16], sgn[16];
#pragma unroll
    for (int d = 0; d < 16; ++d) {
      l2[d] = lu_s[d] + lu_s[16 + d];
      sgn[d] = sg_s[d] * sg_s[16 + d];
      mx = fmaxf(mx, l2[d]);
    }
    float psi = 0.f;
#pragma unroll
    for (int d = 0; d < 16; ++d) psi += sgn[d] * __expf(l2[d] - mx) * wf_w[d];
    out[b] = logf(fabsf(psi)) + mx;
  }
}

}  // namespace

extern "C" void kernel_launch(void* const* d_in, const int* in_sizes, int n_in,
                              void* d_out, int out_size, void* d_ws, size_t ws_size,
                              hipStream_t stream) {
  const float* r = (const float*)d_in[0];
  const float* a = (const float*)d_in[1];
  const float* s_w0 = (const float*)d_in[2];
  const float* s_b0 = (const float*)d_in[3];
  const float* s_w = (const float*)d_in[4];
  const float* s_b = (const float*)d_in[5];
  const float* p_w0 = (const float*)d_in[6];
  const float* p_b0 = (const float*)d_in[7];
  const float* p_w = (const float*)d_in[8];
  const float* p_b = (const float*)d_in[9];
  const float* vu_w = (const float*)d_in[10];
  const float* vu_b = (const float*)d_in[11];
  const float* vd_w = (const float*)d_in[12];
  const float* vd_b = (const float*)d_in[13];
  const float* wu_w = (const float*)d_in[14];
  const float* wu_b = (const float*)d_in[15];
  const float* wd_w = (const float*)d_in[16];
  const float* wd_b = (const float*)d_in[17];
  const float* wf_w = (const float*)d_in[18];

  unsigned short* wsb = (unsigned short*)d_ws;
  float* wspv = (float*)d_ws + PV_OFF_FLOATS;
  const int nb = in_sizes[0] / 60;  // [B,20,3]

  prep_weights<<<dim3(568), dim3(256), 0, stream>>>(s_w, vu_w, vd_w, wu_w, wd_w, s_w0, wsb);

  const size_t need = (size_t)PV_OFF_FLOATS * 4 + (size_t)nb * 12800 * 4;
  if (ws_size >= need) {
    ansatz_fused<true><<<dim3(nb), dim3(256), 0, stream>>>(
        r, a, s_b0, s_b, p_w0, p_b0, p_w, p_b,
        vu_b, vd_b, wu_b, wd_b, wf_w, wsb, wspv, (float*)d_out);
  } else {
    ansatz_fused<false><<<dim3(nb), dim3(256), 0, stream>>>(
        r, a, s_b0, s_b, p_w0, p_b0, p_w, p_b,
        vu_b, vd_b, wu_b, wd_b, wf_w, wsb, wspv, (float*)d_out);
  }
}